// Round 6
// baseline (186.803 us; speedup 1.0000x reference)
//
#include <hip/hip_runtime.h>
#include <hip/hip_bf16.h>

// out = (Q K^T * SCALE) @ V  ==  Q @ (SCALE * K^T V)   (softmax discarded in ref)
// B=32, T=2048, E=1024, H=64.  M = B*T = 65536.
// Chain: k_wt (W transpose->bf16), k_qkv (QKV proj + fused per-block K^T V
// partials), k_red (reduce partials -> KtV^T bf16), k_out (Q @ KtV).

using bf16x8 = __attribute__((ext_vector_type(8))) short;
using f32x4  = __attribute__((ext_vector_type(4))) float;
using u32x4  = __attribute__((ext_vector_type(4))) unsigned int;
using u32x2  = __attribute__((ext_vector_type(2))) unsigned int;
using u16    = unsigned short;

__device__ __forceinline__ u16 f2bf(float f) {
    unsigned u = __builtin_bit_cast(unsigned, f);
    u += 0x7fffu + ((u >> 16) & 1u);          // RNE
    return (u16)(u >> 16);
}

#define G2L16(g, l) __builtin_amdgcn_global_load_lds(                         \
    (const __attribute__((address_space(1))) void*)(g),                       \
    (__attribute__((address_space(3))) void*)(l), 16, 0, 0)

// ---------------- k_wt: WT[n][e] = W*[e][n] as bf16 (LDS transpose) ----------------
__global__ __launch_bounds__(256) void k_wt(const float* __restrict__ Wq,
                                            const float* __restrict__ Wk,
                                            const float* __restrict__ Wv,
                                            u16* __restrict__ WT) {
    __shared__ float Wl[64][68];
    const int seg = blockIdx.x >> 4, chunk = blockIdx.x & 15;   // 48 blocks
    const float* W = (seg == 0) ? Wq : (seg == 1) ? Wk : Wv;
    const int e0 = chunk * 64;
    const int tid = threadIdx.x;
    const int lr = tid >> 4, lc = (tid & 15) * 4;
#pragma unroll
    for (int p = 0; p < 4; ++p)
        *(f32x4*)&Wl[lr + p * 16][lc] = *(const f32x4*)(W + (size_t)(e0 + lr + p * 16) * 64 + lc);
    __syncthreads();
    const int c = tid >> 2, eb = (tid & 3) * 16;
    u32x4 o0, o1;
#pragma unroll
    for (int q = 0; q < 4; ++q)
        o0[q] = (unsigned)f2bf(Wl[eb + 2 * q][c]) | ((unsigned)f2bf(Wl[eb + 2 * q + 1][c]) << 16);
#pragma unroll
    for (int q = 0; q < 4; ++q)
        o1[q] = (unsigned)f2bf(Wl[eb + 8 + 2 * q][c]) | ((unsigned)f2bf(Wl[eb + 9 + 2 * q][c]) << 16);
    u16* dst = WT + (size_t)(seg * 64 + c) * 1024 + e0 + eb;
    *(u32x4*)dst = o0;
    *(u32x4*)(dst + 8) = o1;
}

// ---------------- k_qkv: Q = x@Wq+bq (bf16 out) + fused partial K^T V ----------------
// 256 thr (4 waves, 2M x 2N), M-tile 64, N=192, BK=64, 16 chunks.  TLP-first:
// LDS = x f32 [64][64] TRIPLE buffer (3*16 KB), G2L16 2-deep prefetch, counted
// vmcnt(4); WT NOT staged (L2-resident, B-frags direct from global).  ~3 blk/CU.
// x swizzle: granule-32 XOR ^((r&7)<<5), inverse-applied on DMA source.
__global__ __launch_bounds__(256, 3) void k_qkv(const float* __restrict__ x,
                                                const u16* __restrict__ WT,
                                                const float* __restrict__ bq,
                                                const float* __restrict__ bk,
                                                const float* __restrict__ bv,
                                                u16* __restrict__ Qb,
                                                float* __restrict__ part) {
    __shared__ __align__(16) char lds[49152];     // 3 x-buffers of 16384 B
    const int tid  = threadIdx.x;
    const int wave = tid >> 6, lane = tid & 63;
    const int wr = wave >> 1, wc = wave & 1;      // 2M x 2N wave grid
    const size_t row0 = (size_t)blockIdx.x * 64;

    // staging: 4 G2L16/thread/chunk; dest wave-uniform base, HW adds lane*16.
    size_t xsrc[4]; int xdst[4];
#pragma unroll
    for (int i = 0; i < 4; ++i) {
        const int r    = wave * 16 + i * 4 + (lane >> 4);
        const int csrc = ((lane & 15) * 4) ^ ((r & 7) << 3);   // inverse swz (elems)
        xsrc[i] = (row0 + r) * 1024 + csrc;
        xdst[i] = wave * 4096 + i * 1024;
    }

    f32x4 acc[2][6];
#pragma unroll
    for (int m = 0; m < 2; ++m)
#pragma unroll
        for (int n = 0; n < 6; ++n)
#pragma unroll
            for (int r = 0; r < 4; ++r) acc[m][n][r] = 0.0f;

    // prologue: stage chunks 0,1 into bufs 0,1
#pragma unroll
    for (int i = 0; i < 4; ++i) G2L16(x + xsrc[i], lds + xdst[i]);
#pragma unroll
    for (int i = 0; i < 4; ++i) G2L16(x + xsrc[i] + 64, lds + 16384 + xdst[i]);

    for (int k = 0; k < 16; ++k) {
        // wait chunk k landed (keep chunk k+1's 4 DMAs in flight)
        if (k < 15) asm volatile("s_waitcnt vmcnt(4)" ::: "memory");
        else        asm volatile("s_waitcnt vmcnt(0)" ::: "memory");
        __builtin_amdgcn_s_barrier();             // all waves' DMAs for k done
        if (k + 2 < 16) {                         // stage k+2 (buf freed by k-1)
            char* const dbuf = lds + ((k + 2) % 3) * 16384;
            const int k0 = (k + 2) * 64;
#pragma unroll
            for (int i = 0; i < 4; ++i) G2L16(x + xsrc[i] + k0, dbuf + xdst[i]);
        }

        const char* const xb = lds + (k % 3) * 16384;
        const u16* const wk = WT + k * 64;
#pragma unroll
        for (int ks = 0; ks < 2; ++ks) {
            bf16x8 af[2];
#pragma unroll
            for (int m = 0; m < 2; ++m) {
                const int r_ = wr * 32 + m * 16 + (lane & 15);
                const int P  = (r_ * 256 + ks * 128 + (lane >> 4) * 32) ^ ((r_ & 7) << 5);
                const f32x4 lo = *(const f32x4*)(xb + P);
                const f32x4 hi = *(const f32x4*)(xb + P + 16);
                u32x4 pk;
                pk[0] = (unsigned)f2bf(lo[0]) | ((unsigned)f2bf(lo[1]) << 16);
                pk[1] = (unsigned)f2bf(lo[2]) | ((unsigned)f2bf(lo[3]) << 16);
                pk[2] = (unsigned)f2bf(hi[0]) | ((unsigned)f2bf(hi[1]) << 16);
                pk[3] = (unsigned)f2bf(hi[2]) | ((unsigned)f2bf(hi[3]) << 16);
                af[m] = __builtin_bit_cast(bf16x8, pk);
            }
#pragma unroll
            for (int n = 0; n < 6; ++n) {
                const int nn = wc * 96 + n * 16 + (lane & 15);
                const bf16x8 bfr = *(const bf16x8*)(wk + (size_t)nn * 1024 + ks * 32 + (lane >> 4) * 8);
                acc[0][n] = __builtin_amdgcn_mfma_f32_16x16x32_bf16(af[0], bfr, acc[0][n], 0, 0, 0);
                acc[1][n] = __builtin_amdgcn_mfma_f32_16x16x32_bf16(af[1], bfr, acc[1][n], 0, 0, 0);
            }
        }
    }
    __syncthreads();                              // LDS now free for Kt/Vt

    // ---- epilogue: Q -> global; K,V -> LDS transposed bf16 tiles (+bias) ----
    // D-layout: col = lane&15, row = (lane>>4)*4 + rr
    u16* const Kt = (u16*)lds;                    // [64][72]  (h_k major, 9216 B)
    u16* const Vt = (u16*)(lds + 10240);          // [64][72]  (h_v major)
#pragma unroll
    for (int n = 0; n < 6; ++n) {
        const int ncol = wc * 96 + n * 16;
        const int seg = ncol >> 6;
        const int col = (ncol & 63) + (lane & 15);
        const float bias = ((seg == 0) ? bq : (seg == 1) ? bk : bv)[col];
#pragma unroll
        for (int m = 0; m < 2; ++m) {
            const int rloc = wr * 32 + m * 16 + ((lane >> 4) << 2);
            if (seg == 0) {
#pragma unroll
                for (int rr = 0; rr < 4; ++rr)
                    Qb[(row0 + rloc + rr) * 64 + col] = f2bf(acc[m][n][rr] + bias);
            } else {
                u16* const T = (seg == 1) ? Kt : Vt;
#pragma unroll
                for (int rr = 0; rr < 4; ++rr)
                    T[col * 72 + rloc + rr] = f2bf(acc[m][n][rr] + bias);
            }
        }
    }
    __syncthreads();

    // ---- fused K^T V partial: D[hv][hk] = sum_{64 rows} V[row][hv]*K[row][hk] ----
    float* const P = part + (size_t)blockIdx.x * 4096;
#pragma unroll
    for (int i = 0; i < 4; ++i) {
        const int f = wave * 4 + i;
        const int m0 = (f & 3) * 16;              // h_v
        const int n0 = (f >> 2) * 16;             // h_k
        f32x4 d;
        d[0] = d[1] = d[2] = d[3] = 0.0f;
#pragma unroll
        for (int ks = 0; ks < 2; ++ks) {
            const bf16x8 a = *(const bf16x8*)(Vt + (m0 + (lane & 15)) * 72 + ks * 32 + (lane >> 4) * 8);
            const bf16x8 b = *(const bf16x8*)(Kt + (n0 + (lane & 15)) * 72 + ks * 32 + (lane >> 4) * 8);
            d = __builtin_amdgcn_mfma_f32_16x16x32_bf16(a, b, d, 0, 0, 0);
        }
#pragma unroll
        for (int rr = 0; rr < 4; ++rr)
            P[(m0 + (lane >> 4) * 4 + rr) * 64 + n0 + (lane & 15)] = d[rr];
    }
}

// ---------------- k_red: KtVT[b][o] = SCALE * sum_c part[b*32+c][o], bf16 ----------------
__global__ __launch_bounds__(256) void k_red(const float* __restrict__ part,
                                             u16* __restrict__ KtVT) {
    const int b = blockIdx.x >> 2;
    const int o0 = (blockIdx.x & 3) * 1024 + threadIdx.x * 4;
    const float* const Pb = part + (size_t)b * 32 * 4096;
    f32x4 s;
    s[0] = s[1] = s[2] = s[3] = 0.0f;
#pragma unroll 8
    for (int c = 0; c < 32; ++c) s += *(const f32x4*)(Pb + c * 4096 + o0);
    s *= 0.125f;                                   // SCALE = 64^-0.5
    u32x2 pk;
    pk[0] = (unsigned)f2bf(s[0]) | ((unsigned)f2bf(s[1]) << 16);
    pk[1] = (unsigned)f2bf(s[2]) | ((unsigned)f2bf(s[3]) << 16);
    *(u32x2*)(KtVT + (size_t)b * 4096 + o0) = pk;
}

// ---------------- k_out: out = Q @ KtV (K=64), fp32 out ----------------
__global__ __launch_bounds__(256) void k_out(const u16* __restrict__ Qb,
                                             const u16* __restrict__ KtVT,
                                             float* __restrict__ out) {
    const int tid = threadIdx.x;
    const int wave = tid >> 6, lane = tid & 63;
    const size_t m0 = (size_t)blockIdx.x * 64 + wave * 16;
    const int b = blockIdx.x >> 5;            // 32 blocks per batch
    const u16* const Bp = KtVT + (size_t)b * 4096;

    bf16x8 bfrag[2][4];
#pragma unroll
    for (int ks = 0; ks < 2; ++ks)
#pragma unroll
        for (int nt = 0; nt < 4; ++nt)
            bfrag[ks][nt] = *(const bf16x8*)(Bp + (nt * 16 + (lane & 15)) * 64 + ks * 32 + (lane >> 4) * 8);

    f32x4 acc[4];
#pragma unroll
    for (int nt = 0; nt < 4; ++nt)
#pragma unroll
        for (int r = 0; r < 4; ++r) acc[nt][r] = 0.0f;

#pragma unroll
    for (int ks = 0; ks < 2; ++ks) {
        const bf16x8 a = *(const bf16x8*)(Qb + (m0 + (lane & 15)) * 64 + ks * 32 + (lane >> 4) * 8);
#pragma unroll
        for (int nt = 0; nt < 4; ++nt)
            acc[nt] = __builtin_amdgcn_mfma_f32_16x16x32_bf16(a, bfrag[ks][nt], acc[nt], 0, 0, 0);
    }
#pragma unroll
    for (int nt = 0; nt < 4; ++nt)
#pragma unroll
        for (int rr = 0; rr < 4; ++rr)
            out[(m0 + (lane >> 4) * 4 + rr) * 64 + nt * 16 + (lane & 15)] = acc[nt][rr];
}

extern "C" void kernel_launch(void* const* d_in, const int* in_sizes, int n_in,
                              void* d_out, int out_size, void* d_ws, size_t ws_size,
                              hipStream_t stream) {
    (void)in_sizes; (void)n_in; (void)out_size; (void)ws_size;
    const float* x  = (const float*)d_in[0];
    const float* Wq = (const float*)d_in[1];
    const float* bq = (const float*)d_in[2];
    const float* Wk = (const float*)d_in[3];
    const float* bk = (const float*)d_in[4];
    const float* Wv = (const float*)d_in[5];
    const float* bv = (const float*)d_in[6];
    float* out = (float*)d_out;

    char* ws = (char*)d_ws;                       // layout (~24.6 MB total):
    u16*  WT   = (u16*)(ws);                      // 0x0000000: 384 KB  WT bf16 [192][1024]
    u16*  Qb   = (u16*)(ws + 0x60000);            // 0x0060000: 8 MB    Q bf16 [65536][64]
    float* part= (float*)(ws + 0x860000);         // 0x0860000: 16 MB   partials [1024][64][64] f32
    u16*  KtVT = (u16*)(ws + 0x1860000);          // 0x1860000: 256 KB  KtV^T bf16 [32][64][64]

    k_wt <<<48,   256, 0, stream>>>(Wq, Wk, Wv, WT);
    k_qkv<<<1024, 256, 0, stream>>>(x, WT, bq, bk, bv, Qb, part);
    k_red<<<128,  256, 0, stream>>>(part, KtVT);
    k_out<<<1024, 256, 0, stream>>>(Qb, KtVT, out);
}

// Round 7
// 93.611 us; speedup vs baseline: 1.9955x; 1.9955x over previous
//
#include <hip/hip_runtime.h>
#include <hip/hip_bf16.h>

// out = (Q K^T * SCALE) @ V  ==  Q @ (SCALE * K^T V)   (softmax discarded in ref)
// B=32, T=2048, E=1024, H=64.  M = B*T = 65536.
// k_qkv design: x (HBM stream) -> registers directly (compiler-tracked waits,
// no LDS, no manual vmcnt); WT -> LDS dbuf via reg-staging + raw s_barrier with
// lgkmcnt(0) only (global loads stay in flight across barriers).
// A K-permutation is folded into WT so reg-direct A-loads are coalesced:
//   hardware frag slot kappa = 32ks+8g+j holds logical k = 32ks+16(j>>2)+4g+(j&3).

using bf16x8 = __attribute__((ext_vector_type(8))) short;
using f32x4  = __attribute__((ext_vector_type(4))) float;
using u32x4  = __attribute__((ext_vector_type(4))) unsigned int;
using u32x2  = __attribute__((ext_vector_type(2))) unsigned int;
using u16    = unsigned short;

__device__ __forceinline__ u16 f2bf(float f) {
    unsigned u = __builtin_bit_cast(unsigned, f);
    u += 0x7fffu + ((u >> 16) & 1u);          // RNE
    return (u16)(u >> 16);
}

// ---------------- k_wt: WT[n][c*64+kap] = W[c*64+w][n] (bf16, K-permuted) ----------------
__global__ __launch_bounds__(256) void k_wt(const float* __restrict__ Wq,
                                            const float* __restrict__ Wk,
                                            const float* __restrict__ Wv,
                                            u16* __restrict__ WT) {
    __shared__ float Wl[64][68];
    const int seg = blockIdx.x >> 4, chunk = blockIdx.x & 15;   // 48 blocks
    const float* W = (seg == 0) ? Wq : (seg == 1) ? Wk : Wv;
    const int e0 = chunk * 64;
    const int tid = threadIdx.x;
    const int lr = tid >> 4, lc = (tid & 15) * 4;
#pragma unroll
    for (int p = 0; p < 4; ++p)
        *(f32x4*)&Wl[lr + p * 16][lc] = *(const f32x4*)(W + (size_t)(e0 + lr + p * 16) * 64 + lc);
    __syncthreads();
    const int c = tid >> 2, eb = (tid & 3) * 16;
    u16* const dst = WT + (size_t)(seg * 64 + c) * 1024 + e0;
#pragma unroll
    for (int q = 0; q < 16; ++q) {
        const int w = eb + q;
        const int kap = ((w >> 5) << 5) | (((w >> 2) & 3) << 3) |
                        (((w >> 4) & 1) << 2) | (w & 3);
        dst[kap] = f2bf(Wl[w][c]);
    }
}

// ---------------- k_qkv: Q = x@Wq+bq (bf16 out) + fused partial K^T V ----------------
// 256 thr (4 waves, 4M x 1N), M-tile 64, N=192, BK=64, 16 chunks.
// LDS: WT bf16 [192][64] dbuf 2*24 KB (swz ^((n&7)<<4)) = 48 KB -> 3 blocks/CU.
__global__ __launch_bounds__(256, 3) void k_qkv(const float* __restrict__ x,
                                                const u16* __restrict__ WT,
                                                const float* __restrict__ bq,
                                                const float* __restrict__ bk,
                                                const float* __restrict__ bv,
                                                u16* __restrict__ Qb,
                                                float* __restrict__ part) {
    __shared__ __align__(16) char lds[49152];     // wbuf0 @0, wbuf1 @24576
    const int tid  = threadIdx.x;
    const int wave = tid >> 6, lane = tid & 63;
    const size_t row0 = (size_t)blockIdx.x * 64;

    // x reg-load base: row = wave*16 + (lane&15); lane's 16B-slot group g = lane>>4.
    // chunk c, instr i: 16B at xp + c*64 + i*16  (16 rows x 64 B contiguous / instr)
    const float* const xp = x + (row0 + wave * 16 + (lane & 15)) * 1024 + (lane >> 4) * 4;

    // WT reg-staging: thread covers rows wn+32j (j=0..5), 16B slot wslot.
    const int wn = tid >> 3, wslot = tid & 7;
    const u16* const wpt = WT + (size_t)wn * 1024 + wslot * 8;
    int wdstl[6];
#pragma unroll
    for (int j = 0; j < 6; ++j)
        wdstl[j] = (wn + 32 * j) * 128 + ((wslot * 16) ^ ((wn & 7) << 4));

    f32x4 acc[12];
#pragma unroll
    for (int n = 0; n < 12; ++n)
#pragma unroll
        for (int r = 0; r < 4; ++r) acc[n][r] = 0.0f;

    f32x4 rA[4], rB[4];
    u32x4 wreg[6];

#define WLOAD(C)                                                              \
    { _Pragma("unroll") for (int j = 0; j < 6; ++j)                           \
        wreg[j] = *(const u32x4*)(wpt + (size_t)j * 32768 + (C) * 64); }

#define DSW(BUF)                                                              \
    { char* const b_ = lds + (BUF) * 24576;                                   \
      _Pragma("unroll") for (int j = 0; j < 6; ++j)                           \
        *(u32x4*)(b_ + wdstl[j]) = wreg[j]; }

#define XLOAD(R, C)                                                           \
    { _Pragma("unroll") for (int i = 0; i < 4; ++i)                           \
        R[i] = *(const f32x4*)(xp + (C) * 64 + i * 16); }

#define BARRIER()                                                             \
    { __builtin_amdgcn_sched_barrier(0);                                      \
      asm volatile("s_waitcnt lgkmcnt(0)" ::: "memory");                      \
      __builtin_amdgcn_s_barrier();                                           \
      __builtin_amdgcn_sched_barrier(0); }

#define COMPUTE(CUR, R)                                                       \
    { const char* const wb_ = lds + (CUR) * 24576;                            \
      _Pragma("unroll") for (int ks = 0; ks < 2; ++ks) {                      \
        u32x4 pk_;                                                            \
        pk_[0] = (unsigned)f2bf(R[2*ks][0])   | ((unsigned)f2bf(R[2*ks][1])   << 16); \
        pk_[1] = (unsigned)f2bf(R[2*ks][2])   | ((unsigned)f2bf(R[2*ks][3])   << 16); \
        pk_[2] = (unsigned)f2bf(R[2*ks+1][0]) | ((unsigned)f2bf(R[2*ks+1][1]) << 16); \
        pk_[3] = (unsigned)f2bf(R[2*ks+1][2]) | ((unsigned)f2bf(R[2*ks+1][3]) << 16); \
        const bf16x8 af_ = __builtin_bit_cast(bf16x8, pk_);                   \
        _Pragma("unroll") for (int n = 0; n < 12; ++n) {                      \
          const int nn_ = n * 16 + (lane & 15);                               \
          const bf16x8 bf_ = *(const bf16x8*)(wb_ +                           \
              ((nn_ * 128 + ks * 64 + (lane >> 4) * 16) ^ ((nn_ & 7) << 4))); \
          acc[n] = __builtin_amdgcn_mfma_f32_16x16x32_bf16(af_, bf_, acc[n], 0, 0, 0); \
        } } }

#define PHASE(K, RC)                                                          \
    { if ((K) < 15) DSW(((K) + 1) & 1);                                       \
      if ((K) < 14) WLOAD((K) + 2);                                           \
      COMPUTE((K) & 1, RC);                                                   \
      if ((K) < 14) XLOAD(RC, (K) + 2);                                       \
      BARRIER(); }

    // ---- prologue ----
    WLOAD(0);
    XLOAD(rA, 0);
    XLOAD(rB, 1);
    DSW(0);
    WLOAD(1);
    BARRIER();

    // ---- main loop: 16 chunks, unroll-2 for static x-reg names ----
    for (int kk = 0; kk < 16; kk += 2) {
        PHASE(kk,     rA);
        PHASE(kk + 1, rB);
    }

    // ---- epilogue: Q -> global; K,V -> LDS transposed bf16 tiles (+bias) ----
    // D-layout: col = lane&15, row = (lane>>4)*4 + rr
    u16* const Kt = (u16*)lds;                    // [64][72]  (h_k major, 9216 B)
    u16* const Vt = (u16*)(lds + 10240);          // [64][72]  (h_v major)
    const int rloc = wave * 16 + ((lane >> 4) << 2);
#pragma unroll
    for (int n = 0; n < 12; ++n) {
        const int seg = n >> 2;
        const int col = (n & 3) * 16 + (lane & 15);
        const float bias = ((seg == 0) ? bq : (seg == 1) ? bk : bv)[col];
        if (seg == 0) {
#pragma unroll
            for (int rr = 0; rr < 4; ++rr)
                Qb[(row0 + rloc + rr) * 64 + col] = f2bf(acc[n][rr] + bias);
        } else {
            u16* const T = (seg == 1) ? Kt : Vt;
#pragma unroll
            for (int rr = 0; rr < 4; ++rr)
                T[col * 72 + rloc + rr] = f2bf(acc[n][rr] + bias);
        }
    }
    __syncthreads();

    // ---- fused K^T V partial: D[hv][hk] = sum_{64 rows} V[row][hv]*K[row][hk] ----
    float* const P = part + (size_t)blockIdx.x * 4096;
#pragma unroll
    for (int i = 0; i < 4; ++i) {
        const int f = wave * 4 + i;
        const int m0 = (f & 3) * 16;              // h_v
        const int n0 = (f >> 2) * 16;             // h_k
        f32x4 d;
        d[0] = d[1] = d[2] = d[3] = 0.0f;
#pragma unroll
        for (int ks = 0; ks < 2; ++ks) {
            const bf16x8 a = *(const bf16x8*)(Vt + (m0 + (lane & 15)) * 72 + ks * 32 + (lane >> 4) * 8);
            const bf16x8 b = *(const bf16x8*)(Kt + (n0 + (lane & 15)) * 72 + ks * 32 + (lane >> 4) * 8);
            d = __builtin_amdgcn_mfma_f32_16x16x32_bf16(a, b, d, 0, 0, 0);
        }
#pragma unroll
        for (int rr = 0; rr < 4; ++rr)
            P[(m0 + (lane >> 4) * 4 + rr) * 64 + n0 + (lane & 15)] = d[rr];
    }
#undef PHASE
#undef COMPUTE
#undef BARRIER
#undef XLOAD
#undef DSW
#undef WLOAD
}

// ---------------- k_red: KtVT[b][o] = SCALE * sum_c part[b*32+c][o], bf16 ----------------
__global__ __launch_bounds__(256) void k_red(const float* __restrict__ part,
                                             u16* __restrict__ KtVT) {
    const int b = blockIdx.x >> 2;
    const int o0 = (blockIdx.x & 3) * 1024 + threadIdx.x * 4;
    const float* const Pb = part + (size_t)b * 32 * 4096;
    f32x4 s;
    s[0] = s[1] = s[2] = s[3] = 0.0f;
#pragma unroll 8
    for (int c = 0; c < 32; ++c) s += *(const f32x4*)(Pb + c * 4096 + o0);
    s *= 0.125f;                                   // SCALE = 64^-0.5
    u32x2 pk;
    pk[0] = (unsigned)f2bf(s[0]) | ((unsigned)f2bf(s[1]) << 16);
    pk[1] = (unsigned)f2bf(s[2]) | ((unsigned)f2bf(s[3]) << 16);
    *(u32x2*)(KtVT + (size_t)b * 4096 + o0) = pk;
}

// ---------------- k_out: out = Q @ KtV (K=64), fp32 out ----------------
__global__ __launch_bounds__(256) void k_out(const u16* __restrict__ Qb,
                                             const u16* __restrict__ KtVT,
                                             float* __restrict__ out) {
    const int tid = threadIdx.x;
    const int wave = tid >> 6, lane = tid & 63;
    const size_t m0 = (size_t)blockIdx.x * 64 + wave * 16;
    const int b = blockIdx.x >> 5;            // 32 blocks per batch
    const u16* const Bp = KtVT + (size_t)b * 4096;

    bf16x8 bfrag[2][4];
#pragma unroll
    for (int ks = 0; ks < 2; ++ks)
#pragma unroll
        for (int nt = 0; nt < 4; ++nt)
            bfrag[ks][nt] = *(const bf16x8*)(Bp + (nt * 16 + (lane & 15)) * 64 + ks * 32 + (lane >> 4) * 8);

    f32x4 acc[4];
#pragma unroll
    for (int nt = 0; nt < 4; ++nt)
#pragma unroll
        for (int r = 0; r < 4; ++r) acc[nt][r] = 0.0f;

#pragma unroll
    for (int ks = 0; ks < 2; ++ks) {
        const bf16x8 a = *(const bf16x8*)(Qb + (m0 + (lane & 15)) * 64 + ks * 32 + (lane >> 4) * 8);
#pragma unroll
        for (int nt = 0; nt < 4; ++nt)
            acc[nt] = __builtin_amdgcn_mfma_f32_16x16x32_bf16(a, bfrag[ks][nt], acc[nt], 0, 0, 0);
    }
#pragma unroll
    for (int nt = 0; nt < 4; ++nt)
#pragma unroll
        for (int rr = 0; rr < 4; ++rr)
            out[(m0 + (lane >> 4) * 4 + rr) * 64 + nt * 16 + (lane & 15)] = acc[nt][rr];
}

extern "C" void kernel_launch(void* const* d_in, const int* in_sizes, int n_in,
                              void* d_out, int out_size, void* d_ws, size_t ws_size,
                              hipStream_t stream) {
    (void)in_sizes; (void)n_in; (void)out_size; (void)ws_size;
    const float* x  = (const float*)d_in[0];
    const float* Wq = (const float*)d_in[1];
    const float* bq = (const float*)d_in[2];
    const float* Wk = (const float*)d_in[3];
    const float* bk = (const float*)d_in[4];
    const float* Wv = (const float*)d_in[5];
    const float* bv = (const float*)d_in[6];
    float* out = (float*)d_out;

    char* ws = (char*)d_ws;                       // layout (~24.6 MB total):
    u16*  WT   = (u16*)(ws);                      // 0x0000000: 384 KB  WT bf16 [192][1024] (K-permuted)
    u16*  Qb   = (u16*)(ws + 0x60000);            // 0x0060000: 8 MB    Q bf16 [65536][64]
    float* part= (float*)(ws + 0x860000);         // 0x0860000: 16 MB   partials [1024][64][64] f32
    u16*  KtVT = (u16*)(ws + 0x1860000);          // 0x1860000: 256 KB  KtV^T bf16 [32][64][64]

    k_wt <<<48,   256, 0, stream>>>(Wq, Wk, Wv, WT);
    k_qkv<<<1024, 256, 0, stream>>>(x, WT, bq, bk, bv, Qb, part);
    k_red<<<128,  256, 0, stream>>>(part, KtVT);
    k_out<<<1024, 256, 0, stream>>>(Qb, KtVT, out);
}